// Round 4
// baseline (922.075 us; speedup 1.0000x reference)
//
#include <hip/hip_runtime.h>
#include <hip/hip_bf16.h>

#define NN 50000
#define EE 800000
#define FIN 128
#define HID 96
#define HEADS 4
#define CDIM 24
#define NEG_SLOPE 0.2f
#define BN_EPS 1e-5f

__device__ __forceinline__ float lrelu(float x) { return x > 0.f ? x : NEG_SLOPE * x; }
__device__ __forceinline__ float elu(float x) { return x > 0.f ? x : expm1f(x); }
__device__ __forceinline__ float sel4(float4 v, int h) {
    // branchless component select; h's conditions are loop-invariant -> 3 cndmask
    return (h & 2) ? ((h & 1) ? v.w : v.z) : ((h & 1) ? v.y : v.x);
}

// ---------------- CSR build ----------------
__global__ void count_deg_kernel(const int* __restrict__ dst, int* __restrict__ cnt) {
    int i = blockIdx.x * 256 + threadIdx.x;
    if (i < EE) atomicAdd(&cnt[dst[i]], 1);
}

// single-block exclusive scan, shuffle-based (1024 threads = 16 waves)
__global__ __launch_bounds__(1024) void scan_kernel(const int* __restrict__ cnt,
                                                    int* __restrict__ row_off) {
    __shared__ int wsum[16];
    __shared__ int carry_s;
    int t = threadIdx.x;
    int lane = t & 63, wv = t >> 6;
    if (t == 0) carry_s = 0;
    __syncthreads();
    for (int base = 0; base < NN; base += 1024) {
        int v = (base + t < NN) ? cnt[base + t] : 0;
        int x = v;  // inclusive wave scan
#pragma unroll
        for (int off = 1; off < 64; off <<= 1) {
            int y = __shfl_up(x, off);
            if (lane >= off) x += y;
        }
        if (lane == 63) wsum[wv] = x;
        __syncthreads();
        int wb = 0;
        for (int i = 0; i < wv; i++) wb += wsum[i];
        int c = carry_s;
        if (base + t < NN) row_off[base + t] = c + wb + x - v;  // exclusive
        __syncthreads();
        if (t == 0) {
            int tot = 0;
            for (int i = 0; i < 16; i++) tot += wsum[i];
            carry_s = c + tot;
        }
        __syncthreads();
    }
    if (t == 0) row_off[NN] = EE;
}

__global__ void scatter_kernel(const int* __restrict__ src, const int* __restrict__ dst,
                               const int* __restrict__ row_off, int* __restrict__ cnt,
                               int* __restrict__ col_src) {
    int i = blockIdx.x * 256 + threadIdx.x;
    if (i < EE) {
        int d = dst[i];
        int pos = atomicAdd(&cnt[d], 1);
        col_src[row_off[d] + pos] = src[i];
    }
}

// ---------------- GEMM: H = X @ W (+ optional fused BN+ELU on X) + alpha epilogue
// block: 256 thr = 16 rows x 16 col-groups of 6. Each thread's 6 cols lie within
// ONE head (6i mod 24 in {0,6,12,18}) -> alpha dot reduces over 4 lanes.
template <int K, bool BN>
__global__ __launch_bounds__(256) void gemm_kernel(const float* __restrict__ X,
                                                   const float* __restrict__ W,
                                                   const float* __restrict__ a_s,
                                                   const float* __restrict__ a_d,
                                                   const float* __restrict__ ss,
                                                   float* __restrict__ H,
                                                   float* __restrict__ As,
                                                   float* __restrict__ Ad) {
    __shared__ float Ws[K * 96];
    __shared__ float Xs[16 * K];
    int t = threadIdx.x;
    for (int i = t; i < K * 24; i += 256) ((float4*)Ws)[i] = ((const float4*)W)[i];
    int row0 = blockIdx.x * 16;
    const float4* X4 = (const float4*)(X + (size_t)row0 * K);
    if (BN) {
        // X is pre-BN: apply gamma/beta affine + ELU while staging (K==96 path)
        for (int i = t; i < 4 * K; i += 256) {
            float4 v = X4[i];
            int f = (i % (K / 4)) * 4;  // feature col of v.x
            v.x = elu(v.x * ss[f + 0] + ss[96 + f + 0]);
            v.y = elu(v.y * ss[f + 1] + ss[96 + f + 1]);
            v.z = elu(v.z * ss[f + 2] + ss[96 + f + 2]);
            v.w = elu(v.w * ss[f + 3] + ss[96 + f + 3]);
            ((float4*)Xs)[i] = v;
        }
    } else {
        for (int i = t; i < 4 * K; i += 256) ((float4*)Xs)[i] = X4[i];
    }
    __syncthreads();
    int r = t >> 4;
    int i16 = t & 15;
    int c0 = i16 * 6;
    float acc[6] = {0.f, 0.f, 0.f, 0.f, 0.f, 0.f};
#pragma unroll 4
    for (int k = 0; k < K; k++) {
        float xv = Xs[r * K + k];
        const float* wr = &Ws[k * 96 + c0];
#pragma unroll
        for (int j = 0; j < 6; j++) acc[j] += xv * wr[j];
    }
    float* outp = H + (size_t)(row0 + r) * 96 + c0;
#pragma unroll
    for (int j = 0; j < 6; j++) outp[j] = acc[j];

    // fused alpha logits (a_s/a_d are [4][24] flat = 96, so flat index == col)
    int hh = i16 >> 2;  // c0/24
    const float* asl = a_s + c0;
    const float* adl = a_d + c0;
    float ps = 0.f, pd = 0.f;
#pragma unroll
    for (int j = 0; j < 6; j++) {
        ps += acc[j] * asl[j];
        pd += acc[j] * adl[j];
    }
    ps += __shfl_xor(ps, 1); ps += __shfl_xor(ps, 2);
    pd += __shfl_xor(pd, 1); pd += __shfl_xor(pd, 2);
    if ((t & 3) == 0) {
        As[(row0 + r) * 4 + hh] = ps;
        Ad[(row0 + r) * 4 + hh] = pd;
    }
}

// ---------------- global per-head max of As (softmax stabilizer bound) -------
__global__ __launch_bounds__(256) void amax1_kernel(const float* __restrict__ As,
                                                    float4* __restrict__ part) {
    int t = threadIdx.x;
    float4 m = {-3.4e38f, -3.4e38f, -3.4e38f, -3.4e38f};
    for (int i = blockIdx.x * 256 + t; i < NN; i += 128 * 256) {
        float4 v = ((const float4*)As)[i];
        m.x = fmaxf(m.x, v.x); m.y = fmaxf(m.y, v.y);
        m.z = fmaxf(m.z, v.z); m.w = fmaxf(m.w, v.w);
    }
#pragma unroll
    for (int off = 1; off < 64; off <<= 1) {
        m.x = fmaxf(m.x, __shfl_xor(m.x, off));
        m.y = fmaxf(m.y, __shfl_xor(m.y, off));
        m.z = fmaxf(m.z, __shfl_xor(m.z, off));
        m.w = fmaxf(m.w, __shfl_xor(m.w, off));
    }
    __shared__ float4 lm[4];
    if ((t & 63) == 0) lm[t >> 6] = m;
    __syncthreads();
    if (t == 0) {
        for (int i = 1; i < 4; i++) {
            m.x = fmaxf(m.x, lm[i].x); m.y = fmaxf(m.y, lm[i].y);
            m.z = fmaxf(m.z, lm[i].z); m.w = fmaxf(m.w, lm[i].w);
        }
        part[blockIdx.x] = m;
    }
}

__global__ void amax2_kernel(const float4* __restrict__ part, float4* __restrict__ M) {
    int lane = threadIdx.x;  // 64 threads, 1 wave
    float4 a = part[lane], b = part[lane + 64];
    float4 m;
    m.x = fmaxf(a.x, b.x); m.y = fmaxf(a.y, b.y);
    m.z = fmaxf(a.z, b.z); m.w = fmaxf(a.w, b.w);
#pragma unroll
    for (int off = 1; off < 64; off <<= 1) {
        m.x = fmaxf(m.x, __shfl_xor(m.x, off));
        m.y = fmaxf(m.y, __shfl_xor(m.y, off));
        m.z = fmaxf(m.z, __shfl_xor(m.z, off));
        m.w = fmaxf(m.w, __shfl_xor(m.w, off));
    }
    if (lane == 0) *M = m;
}

// ---------------- aggregation: wave per node, SINGLE pass (global-max bound) --
// m_h = lrelu(M_h + Ad_h[n]) >= every incoming logit (lrelu monotone), so
// softmax is computed in one pass; each lane handles only its own head(s).
__global__ __launch_bounds__(256) void agg_kernel(const float* __restrict__ H,
                                                  const float* __restrict__ As,
                                                  const float* __restrict__ Ad,
                                                  const float4* __restrict__ M4,
                                                  const int* __restrict__ row_off,
                                                  const int* __restrict__ col_src,
                                                  const float* __restrict__ bias,
                                                  float* __restrict__ out) {
    int wave = threadIdx.x >> 6;
    int lane = threadIdx.x & 63;
    int n = blockIdx.x * 4 + wave;
    if (n >= NN) return;
    int f1 = lane;            // feature 0..63   (head 0..2)
    int f2 = lane + 64;       // feature 64..95  (head 2..3, lanes 0..31)
    int h1 = f1 / CDIM;
    int h2 = f2 / CDIM;
    float4 ad = ((const float4*)Ad)[n];
    float4 M = *M4;
    float ad1 = sel4(ad, h1);
    float ad2 = sel4(ad, h2);
    float m1 = lrelu(sel4(M, h1) + ad1);
    float m2 = lrelu(sel4(M, h2) + ad2);
    int beg = row_off[n], end = row_off[n + 1];

    float s1 = 0.f, s2 = 0.f, acc1 = 0.f, acc2 = 0.f;
    {   // self-loop term
        float4 a = ((const float4*)As)[n];
        float p1 = __expf(lrelu(sel4(a, h1) + ad1) - m1);
        s1 += p1;
        acc1 += p1 * H[(size_t)n * 96 + f1];
        if (lane < 32) {
            float p2 = __expf(lrelu(sel4(a, h2) + ad2) - m2);
            s2 += p2;
            acc2 += p2 * H[(size_t)n * 96 + f2];
        }
    }
    for (int e = beg; e < end; e++) {
        int s = col_src[e];
        float4 a = ((const float4*)As)[s];
        float p1 = __expf(lrelu(sel4(a, h1) + ad1) - m1);
        s1 += p1;
        acc1 += p1 * H[(size_t)s * 96 + f1];
        if (lane < 32) {
            float p2 = __expf(lrelu(sel4(a, h2) + ad2) - m2);
            s2 += p2;
            acc2 += p2 * H[(size_t)s * 96 + f2];
        }
    }
    out[(size_t)n * 96 + f1] = acc1 / (s1 + 1e-16f) + bias[f1];
    if (lane < 32) out[(size_t)n * 96 + f2] = acc2 / (s2 + 1e-16f) + bias[f2];
}

// ---------------- BatchNorm stats (float4; thread-invariant feature quad) -----
__global__ __launch_bounds__(192) void bn_stats_kernel(const float* __restrict__ Y,
                                                       float* __restrict__ accum) {
    int t = threadIdx.x;
    float4 s = {0.f, 0.f, 0.f, 0.f}, q = {0.f, 0.f, 0.f, 0.f};
    // stride 512*192 = 98304 ≡ 0 (mod 24) -> feature quad fixed per thread
    for (int i4 = blockIdx.x * 192 + t; i4 < NN * 24; i4 += 512 * 192) {
        float4 v = ((const float4*)Y)[i4];
        s.x += v.x; s.y += v.y; s.z += v.z; s.w += v.w;
        q.x += v.x * v.x; q.y += v.y * v.y; q.z += v.z * v.z; q.w += v.w * v.w;
    }
    __shared__ float4 ls[192], lq[192];
    ls[t] = s;
    lq[t] = q;
    __syncthreads();
    if (t < 24) {
        float4 S = ls[t], Q = lq[t];
        for (int i = 1; i < 8; i++) {
            float4 a = ls[t + 24 * i], b = lq[t + 24 * i];
            S.x += a.x; S.y += a.y; S.z += a.z; S.w += a.w;
            Q.x += b.x; Q.y += b.y; Q.z += b.z; Q.w += b.w;
        }
        int f = t * 4;
        atomicAdd(&accum[f + 0], S.x); atomicAdd(&accum[f + 1], S.y);
        atomicAdd(&accum[f + 2], S.z); atomicAdd(&accum[f + 3], S.w);
        atomicAdd(&accum[96 + f + 0], Q.x); atomicAdd(&accum[96 + f + 1], Q.y);
        atomicAdd(&accum[96 + f + 2], Q.z); atomicAdd(&accum[96 + f + 3], Q.w);
    }
}

__global__ void bn_final_kernel(const float* __restrict__ accum, const float* __restrict__ g,
                                const float* __restrict__ bt, float* __restrict__ ss) {
    int f = threadIdx.x;
    if (f >= 96) return;
    float mean = accum[f] * (1.0f / NN);
    float var = accum[96 + f] * (1.0f / NN) - mean * mean;
    float sc = g[f] * rsqrtf(var + BN_EPS);
    ss[f] = sc;
    ss[96 + f] = bt[f] - mean * sc;
}

// ---------------- BN apply + ELU (only after last GAT layer) ----------------
__global__ void bn_apply_kernel(float* __restrict__ Y, const float* __restrict__ ss) {
    int i4 = blockIdx.x * 256 + threadIdx.x;
    if (i4 >= NN * 24) return;
    float4 v = ((float4*)Y)[i4];
    int f = (i4 % 24) * 4;
    v.x = elu(v.x * ss[f + 0] + ss[96 + f + 0]);
    v.y = elu(v.y * ss[f + 1] + ss[96 + f + 1]);
    v.z = elu(v.z * ss[f + 2] + ss[96 + f + 2]);
    v.w = elu(v.w * ss[f + 3] + ss[96 + f + 3]);
    ((float4*)Y)[i4] = v;
}

// ---------------- final FC: out = Y @ fcW + fcb ----------------
__global__ __launch_bounds__(256) void fc_kernel(const float* __restrict__ Y,
                                                 const float* __restrict__ W,
                                                 const float* __restrict__ b,
                                                 float* __restrict__ out) {
    __shared__ float w[96 * 8];
    __shared__ float bb[8];
    int t = threadIdx.x;
    for (int i = t; i < 768; i += 256) w[i] = W[i];
    if (t < 8) bb[t] = b[t];
    __syncthreads();
    int idx = blockIdx.x * 256 + t;
    if (idx >= NN * 8) return;
    int n = idx >> 3, cl = idx & 7;
    const float* yr = Y + (size_t)n * 96;
    float acc = bb[cl];
#pragma unroll 8
    for (int k = 0; k < 96; k++) acc += yr[k] * w[k * 8 + cl];
    out[idx] = acc;
}

extern "C" void kernel_launch(void* const* d_in, const int* in_sizes, int n_in,
                              void* d_out, int out_size, void* d_ws, size_t ws_size,
                              hipStream_t stream) {
    const float* x = (const float*)d_in[0];
    const int* ei = (const int*)d_in[1];
    const int* srcE = ei;
    const int* dstE = ei + EE;
    const float* Wl[3] = {(const float*)d_in[2], (const float*)d_in[8], (const float*)d_in[14]};
    const float* asl[3] = {(const float*)d_in[3], (const float*)d_in[9], (const float*)d_in[15]};
    const float* adl[3] = {(const float*)d_in[4], (const float*)d_in[10], (const float*)d_in[16]};
    const float* bl[3] = {(const float*)d_in[5], (const float*)d_in[11], (const float*)d_in[17]};
    const float* gl[3] = {(const float*)d_in[6], (const float*)d_in[12], (const float*)d_in[18]};
    const float* btl[3] = {(const float*)d_in[7], (const float*)d_in[13], (const float*)d_in[19]};
    const float* fcW = (const float*)d_in[20];
    const float* fcb = (const float*)d_in[21];
    float* out = (float*)d_out;

    // workspace layout (16B-aligned slices)
    char* w = (char*)d_ws;
    float* bufA = (float*)w;            w += (size_t)NN * 96 * 4;   // GEMM output h
    float* bufB = (float*)w;            w += (size_t)NN * 96 * 4;   // aggregated (pre-BN)
    float* alpha_s = (float*)w;         w += (size_t)NN * 4 * 4;
    float* alpha_d = (float*)w;         w += (size_t)NN * 4 * 4;
    float* bn_accum = (float*)w;        w += 192 * 4;
    float* bn_ss = (float*)w;           w += 192 * 4;
    float4* amax_part = (float4*)w;     w += 128 * 16;
    float4* Mbuf = (float4*)w;          w += 16;
    int* row_off = (int*)w;             w += (size_t)(NN + 4) * 4;
    int* cnt = (int*)w;                 w += (size_t)NN * 4;
    int* col_src = (int*)w;             w += (size_t)EE * 4;

    // ---- CSR build (per call; ws is re-poisoned every launch) ----
    hipMemsetAsync(cnt, 0, (size_t)NN * 4, stream);
    count_deg_kernel<<<(EE + 255) / 256, 256, 0, stream>>>(dstE, cnt);
    scan_kernel<<<1, 1024, 0, stream>>>(cnt, row_off);
    hipMemsetAsync(cnt, 0, (size_t)NN * 4, stream);
    scatter_kernel<<<(EE + 255) / 256, 256, 0, stream>>>(srcE, dstE, row_off, cnt, col_src);

    for (int l = 0; l < 3; l++) {
        if (l == 0)
            gemm_kernel<128, false><<<NN / 16, 256, 0, stream>>>(x, Wl[l], asl[l], adl[l],
                                                                 nullptr, bufA, alpha_s, alpha_d);
        else
            gemm_kernel<96, true><<<NN / 16, 256, 0, stream>>>(bufB, Wl[l], asl[l], adl[l],
                                                               bn_ss, bufA, alpha_s, alpha_d);
        amax1_kernel<<<128, 256, 0, stream>>>(alpha_s, amax_part);
        amax2_kernel<<<1, 64, 0, stream>>>(amax_part, Mbuf);
        agg_kernel<<<(NN + 3) / 4, 256, 0, stream>>>(bufA, alpha_s, alpha_d, Mbuf, row_off,
                                                     col_src, bl[l], bufB);
        hipMemsetAsync(bn_accum, 0, 192 * 4, stream);
        bn_stats_kernel<<<512, 192, 0, stream>>>(bufB, bn_accum);
        bn_final_kernel<<<1, 128, 0, stream>>>(bn_accum, gl[l], btl[l], bn_ss);
        // BN+ELU for l=0,1 is fused into the next layer's GEMM staging;
        // materialize only after the last layer (feeds FC).
        if (l == 2)
            bn_apply_kernel<<<(NN * 24 + 255) / 256, 256, 0, stream>>>(bufB, bn_ss);
    }
    fc_kernel<<<(NN * 8 + 255) / 256, 256, 0, stream>>>(bufB, fcW, fcb, out);
}

// Round 7
// 710.323 us; speedup vs baseline: 1.2981x; 1.2981x over previous
//
#include <hip/hip_runtime.h>
#include <hip/hip_bf16.h>

#define NN 50000
#define EE 800000
#define FIN 128
#define HID 96
#define HEADS 4
#define CDIM 24
#define NEG_SLOPE 0.2f
#define BN_EPS 1e-5f
#define NPART 196  // ceil(NN/256)

__device__ __forceinline__ float lrelu(float x) { return x > 0.f ? x : NEG_SLOPE * x; }
__device__ __forceinline__ float elu(float x) { return x > 0.f ? x : expm1f(x); }
__device__ __forceinline__ float sel4(float4 v, int h) {
    return (h & 2) ? ((h & 1) ? v.w : v.z) : ((h & 1) ? v.y : v.x);
}
// order-preserving float<->uint for atomicMax; memset-0 == -inf sentinel
__device__ __forceinline__ unsigned fenc(float f) {
    unsigned b = __float_as_uint(f);
    return (b & 0x80000000u) ? ~b : (b | 0x80000000u);
}
__device__ __forceinline__ float fdec(unsigned u) {
    return (u & 0x80000000u) ? __uint_as_float(u & 0x7FFFFFFFu) : __uint_as_float(~u);
}

// ---------------- CSR build ----------------
__global__ void count_deg_kernel(const int* __restrict__ dst, int* __restrict__ cnt) {
    int i = blockIdx.x * 256 + threadIdx.x;
    if (i < EE) atomicAdd(&cnt[dst[i]], 1);
}

__global__ __launch_bounds__(256) void scan_part_kernel(const int* __restrict__ cnt,
                                                        int* __restrict__ part) {
    int t = threadIdx.x;
    int i = blockIdx.x * 256 + t;
    int v = (i < NN) ? cnt[i] : 0;
#pragma unroll
    for (int off = 1; off < 64; off <<= 1) v += __shfl_xor(v, off);
    __shared__ int ws[4];
    if ((t & 63) == 0) ws[t >> 6] = v;
    __syncthreads();
    if (t == 0) part[blockIdx.x] = ws[0] + ws[1] + ws[2] + ws[3];
}

__global__ __launch_bounds__(256) void scan_partsum_kernel(int* __restrict__ part) {
    int t = threadIdx.x;
    int lane = t & 63, wv = t >> 6;
    int v = (t < NPART) ? part[t] : 0;
    int x = v;
#pragma unroll
    for (int off = 1; off < 64; off <<= 1) {
        int y = __shfl_up(x, off);
        if (lane >= off) x += y;
    }
    __shared__ int wsum[4];
    if (lane == 63) wsum[wv] = x;
    __syncthreads();
    int wb = 0;
    for (int i = 0; i < wv; i++) wb += wsum[i];
    if (t < NPART) part[t] = wb + x - v;  // exclusive
}

__global__ __launch_bounds__(256) void scan_final_kernel(const int* __restrict__ cnt,
                                                         const int* __restrict__ part,
                                                         int* __restrict__ row_off) {
    int t = threadIdx.x;
    int i = blockIdx.x * 256 + t;
    int lane = t & 63, wv = t >> 6;
    int v = (i < NN) ? cnt[i] : 0;
    int x = v;
#pragma unroll
    for (int off = 1; off < 64; off <<= 1) {
        int y = __shfl_up(x, off);
        if (lane >= off) x += y;
    }
    __shared__ int wsum[4];
    if (lane == 63) wsum[wv] = x;
    __syncthreads();
    int wb = 0;
    for (int j = 0; j < wv; j++) wb += wsum[j];
    if (i < NN) row_off[i] = part[blockIdx.x] + wb + x - v;
    if (i == NN) row_off[NN] = EE;
}

// scatter via atomicSub on populated cnt (fills positions deg-1..0)
__global__ void scatter_kernel(const int* __restrict__ src, const int* __restrict__ dst,
                               const int* __restrict__ row_off, int* __restrict__ cnt,
                               int* __restrict__ col_src) {
    int i = blockIdx.x * 256 + threadIdx.x;
    if (i < EE) {
        int d = dst[i];
        int pos = atomicSub(&cnt[d], 1) - 1;
        col_src[row_off[d] + pos] = src[i];
    }
}

// ---------------- GEMM: H = X @ W, K-chunked (KC=32), fused BN+ELU on X,
// fused alpha logits + global As-max (ordered-uint atomics).
// 256 thr = 16 col-groups x 16 row-slots; thread owns rows {r, r+16}, cols c0..c0+5.
template <int K, bool BN>
__global__ __launch_bounds__(256) void gemm_kernel(const float* __restrict__ X,
                                                   const float* __restrict__ W,
                                                   const float* __restrict__ a_s,
                                                   const float* __restrict__ a_d,
                                                   const float* __restrict__ ss,
                                                   float* __restrict__ H,
                                                   float* __restrict__ As,
                                                   float* __restrict__ Ad,
                                                   unsigned* __restrict__ amaxU) {
    const int KC = 32;
    __shared__ float Ws[KC * 96];      // 12 KB
    __shared__ float Xs[32][KC + 4];   // 4.6 KB, stride 36 (16B-aligned quads, 2-way max)
    __shared__ unsigned amx[4];
    int t = threadIdx.x;
    if (t < 4) amx[t] = 0u;
    int row0 = blockIdx.x * 32;
    int r = t >> 4;
    int i16 = t & 15;
    int c0 = i16 * 6;
    int slr = t >> 3;   // staging: node row 0..31
    int sq = t & 7;     // staging: quad 0..7 within chunk
    float accA[6] = {0.f, 0.f, 0.f, 0.f, 0.f, 0.f};
    float accB[6] = {0.f, 0.f, 0.f, 0.f, 0.f, 0.f};
    for (int k0 = 0; k0 < K; k0 += KC) {
        for (int i = t; i < KC * 24; i += 256)
            ((float4*)Ws)[i] = ((const float4*)(W + (size_t)k0 * 96))[i];
        {
            float4 v = make_float4(0.f, 0.f, 0.f, 0.f);
            if (row0 + slr < NN) {
                v = *(const float4*)(X + (size_t)(row0 + slr) * K + k0 + sq * 4);
                if (BN) {
                    int f = k0 + sq * 4;
                    v.x = elu(v.x * ss[f + 0] + ss[96 + f + 0]);
                    v.y = elu(v.y * ss[f + 1] + ss[96 + f + 1]);
                    v.z = elu(v.z * ss[f + 2] + ss[96 + f + 2]);
                    v.w = elu(v.w * ss[f + 3] + ss[96 + f + 3]);
                }
            }
            *(float4*)(&Xs[slr][sq * 4]) = v;
        }
        __syncthreads();
#pragma unroll
        for (int k = 0; k < KC; k++) {
            float va = Xs[r][k];
            float vb = Xs[r + 16][k];
            const float* wr = &Ws[k * 96 + c0];
#pragma unroll
            for (int j = 0; j < 6; j++) {
                accA[j] += va * wr[j];
                accB[j] += vb * wr[j];
            }
        }
        __syncthreads();
    }
    int gA = row0 + r, gB = row0 + 16 + r;  // gA always < NN (NN%32==16)
    float* outA = H + (size_t)gA * 96 + c0;
#pragma unroll
    for (int j = 0; j < 6; j++) outA[j] = accA[j];
    if (gB < NN) {
        float* outB = H + (size_t)gB * 96 + c0;
#pragma unroll
        for (int j = 0; j < 6; j++) outB[j] = accB[j];
    }

    // alpha logits (a_s/a_d flat [96]; flat idx == col)
    int hh = i16 >> 2;
    const float* asl = a_s + c0;
    const float* adl = a_d + c0;
    float psA = 0.f, pdA = 0.f, psB = 0.f, pdB = 0.f;
#pragma unroll
    for (int j = 0; j < 6; j++) {
        psA += accA[j] * asl[j];
        pdA += accA[j] * adl[j];
        psB += accB[j] * asl[j];
        pdB += accB[j] * adl[j];
    }
    psA += __shfl_xor(psA, 1); psA += __shfl_xor(psA, 2);
    pdA += __shfl_xor(pdA, 1); pdA += __shfl_xor(pdA, 2);
    psB += __shfl_xor(psB, 1); psB += __shfl_xor(psB, 2);
    pdB += __shfl_xor(pdB, 1); pdB += __shfl_xor(pdB, 2);
    if ((t & 3) == 0) {
        As[gA * 4 + hh] = psA;
        Ad[gA * 4 + hh] = pdA;
        if (gB < NN) {
            As[gB * 4 + hh] = psB;
            Ad[gB * 4 + hh] = pdB;
        }
    }
    // global per-head max of As: wave-reduce over row slots, LDS-stage, 4 atomics
    float psMax = (gB < NN) ? fmaxf(psA, psB) : psA;
    psMax = fmaxf(psMax, __shfl_xor(psMax, 16));
    psMax = fmaxf(psMax, __shfl_xor(psMax, 32));
    if ((t & 51) == 0) atomicMax(&amx[hh], fenc(psMax));
    __syncthreads();
    if (t < 4) atomicMax(&amaxU[t], amx[t]);
}

// ---------------- aggregation: wave/node, single pass, 4x edge unroll --------
__global__ __launch_bounds__(256) void agg_kernel(const float* __restrict__ H,
                                                  const float* __restrict__ As,
                                                  const float* __restrict__ Ad,
                                                  const unsigned* __restrict__ Mu,
                                                  const int* __restrict__ row_off,
                                                  const int* __restrict__ col_src,
                                                  const float* __restrict__ bias,
                                                  float* __restrict__ out) {
    int wave = threadIdx.x >> 6;
    int lane = threadIdx.x & 63;
    int n = blockIdx.x * 4 + wave;
    if (n >= NN) return;
    int f1 = lane;
    int f2 = lane + 64;
    int h1 = f1 / CDIM;
    int h2 = f2 / CDIM;
    const float4* As4 = (const float4*)As;
    float4 ad = ((const float4*)Ad)[n];
    float4 M = make_float4(fdec(Mu[0]), fdec(Mu[1]), fdec(Mu[2]), fdec(Mu[3]));
    float ad1 = sel4(ad, h1);
    float ad2 = sel4(ad, h2);
    float m1 = lrelu(sel4(M, h1) + ad1);
    float m2 = lrelu(sel4(M, h2) + ad2);
    int beg = row_off[n], end = row_off[n + 1];

    float s1 = 0.f, s2 = 0.f, acc1 = 0.f, acc2 = 0.f;
    {   // self-loop
        float4 a = As4[n];
        float p = __expf(lrelu(sel4(a, h1) + ad1) - m1);
        s1 += p;
        acc1 += p * H[(size_t)n * 96 + f1];
        if (lane < 32) {
            float q = __expf(lrelu(sel4(a, h2) + ad2) - m2);
            s2 += q;
            acc2 += q * H[(size_t)n * 96 + f2];
        }
    }
    int e = beg;
    for (; e + 4 <= end; e += 4) {
        int sa = col_src[e], sb = col_src[e + 1], sc = col_src[e + 2], sd = col_src[e + 3];
        float4 a0 = As4[sa], a1 = As4[sb], a2 = As4[sc], a3 = As4[sd];
        float g0 = H[(size_t)sa * 96 + f1];
        float g1 = H[(size_t)sb * 96 + f1];
        float g2 = H[(size_t)sc * 96 + f1];
        float g3 = H[(size_t)sd * 96 + f1];
        float p0 = __expf(lrelu(sel4(a0, h1) + ad1) - m1);
        float p1 = __expf(lrelu(sel4(a1, h1) + ad1) - m1);
        float p2 = __expf(lrelu(sel4(a2, h1) + ad1) - m1);
        float p3 = __expf(lrelu(sel4(a3, h1) + ad1) - m1);
        s1 += p0; s1 += p1; s1 += p2; s1 += p3;
        acc1 += p0 * g0; acc1 += p1 * g1; acc1 += p2 * g2; acc1 += p3 * g3;
        if (lane < 32) {
            float u0 = H[(size_t)sa * 96 + f2];
            float u1 = H[(size_t)sb * 96 + f2];
            float u2 = H[(size_t)sc * 96 + f2];
            float u3 = H[(size_t)sd * 96 + f2];
            float q0 = __expf(lrelu(sel4(a0, h2) + ad2) - m2);
            float q1 = __expf(lrelu(sel4(a1, h2) + ad2) - m2);
            float q2 = __expf(lrelu(sel4(a2, h2) + ad2) - m2);
            float q3 = __expf(lrelu(sel4(a3, h2) + ad2) - m2);
            s2 += q0; s2 += q1; s2 += q2; s2 += q3;
            acc2 += q0 * u0; acc2 += q1 * u1; acc2 += q2 * u2; acc2 += q3 * u3;
        }
    }
    for (; e < end; e++) {
        int s = col_src[e];
        float4 a = As4[s];
        float p = __expf(lrelu(sel4(a, h1) + ad1) - m1);
        s1 += p;
        acc1 += p * H[(size_t)s * 96 + f1];
        if (lane < 32) {
            float q = __expf(lrelu(sel4(a, h2) + ad2) - m2);
            s2 += q;
            acc2 += q * H[(size_t)s * 96 + f2];
        }
    }
    out[(size_t)n * 96 + f1] = acc1 / (s1 + 1e-16f) + bias[f1];
    if (lane < 32) out[(size_t)n * 96 + f2] = acc2 / (s2 + 1e-16f) + bias[f2];
}

// ---------------- BatchNorm stats (float4; thread-invariant feature quad) -----
__global__ __launch_bounds__(192) void bn_stats_kernel(const float* __restrict__ Y,
                                                       float* __restrict__ accum) {
    int t = threadIdx.x;
    float4 s = {0.f, 0.f, 0.f, 0.f}, q = {0.f, 0.f, 0.f, 0.f};
    for (int i4 = blockIdx.x * 192 + t; i4 < NN * 24; i4 += 512 * 192) {
        float4 v = ((const float4*)Y)[i4];
        s.x += v.x; s.y += v.y; s.z += v.z; s.w += v.w;
        q.x += v.x * v.x; q.y += v.y * v.y; q.z += v.z * v.z; q.w += v.w * v.w;
    }
    __shared__ float4 ls[192], lq[192];
    ls[t] = s;
    lq[t] = q;
    __syncthreads();
    if (t < 24) {
        float4 S = ls[t], Q = lq[t];
        for (int i = 1; i < 8; i++) {
            float4 a = ls[t + 24 * i], b = lq[t + 24 * i];
            S.x += a.x; S.y += a.y; S.z += a.z; S.w += a.w;
            Q.x += b.x; Q.y += b.y; Q.z += b.z; Q.w += b.w;
        }
        int f = t * 4;
        atomicAdd(&accum[f + 0], S.x); atomicAdd(&accum[f + 1], S.y);
        atomicAdd(&accum[f + 2], S.z); atomicAdd(&accum[f + 3], S.w);
        atomicAdd(&accum[96 + f + 0], Q.x); atomicAdd(&accum[96 + f + 1], Q.y);
        atomicAdd(&accum[96 + f + 2], Q.z); atomicAdd(&accum[96 + f + 3], Q.w);
    }
}

__global__ void bn_final_kernel(const float* __restrict__ accum, const float* __restrict__ g,
                                const float* __restrict__ bt, float* __restrict__ ss) {
    int f = threadIdx.x;
    if (f >= 96) return;
    float mean = accum[f] * (1.0f / NN);
    float var = accum[96 + f] * (1.0f / NN) - mean * mean;
    float sc = g[f] * rsqrtf(var + BN_EPS);
    ss[f] = sc;
    ss[96 + f] = bt[f] - mean * sc;
}

// ---------------- final FC with fused BN+ELU: out = elu(bn(Y)) @ fcW + fcb ---
__global__ __launch_bounds__(256) void fc_kernel(const float* __restrict__ Y,
                                                 const float* __restrict__ ss,
                                                 const float* __restrict__ W,
                                                 const float* __restrict__ b,
                                                 float* __restrict__ out) {
    __shared__ float w[96 * 8];
    __shared__ float yl[32][100];  // padded stride (16B-aligned, conflict-free)
    __shared__ float bb[8];
    int t = threadIdx.x;
    for (int i = t; i < 768; i += 256) w[i] = W[i];
    if (t < 8) bb[t] = b[t];
    int row0 = blockIdx.x * 32;
    for (int i = t; i < 768; i += 256) {  // 32 rows x 24 quads
        int lr = i / 24, q = i % 24;
        float4 v = make_float4(0.f, 0.f, 0.f, 0.f);
        if (row0 + lr < NN) {
            v = *(const float4*)(Y + (size_t)(row0 + lr) * 96 + q * 4);
            int f = q * 4;
            v.x = elu(v.x * ss[f + 0] + ss[96 + f + 0]);
            v.y = elu(v.y * ss[f + 1] + ss[96 + f + 1]);
            v.z = elu(v.z * ss[f + 2] + ss[96 + f + 2]);
            v.w = elu(v.w * ss[f + 3] + ss[96 + f + 3]);
        }
        *(float4*)(&yl[lr][q * 4]) = v;
    }
    __syncthreads();
    int ln = t >> 3;  // local node 0..31
    int cl = t & 7;
    int n = row0 + ln;
    if (n >= NN) return;
    float acc = bb[cl];
#pragma unroll 8
    for (int k = 0; k < 96; k++) acc += yl[ln][k] * w[k * 8 + cl];
    out[(size_t)n * 8 + cl] = acc;
}

extern "C" void kernel_launch(void* const* d_in, const int* in_sizes, int n_in,
                              void* d_out, int out_size, void* d_ws, size_t ws_size,
                              hipStream_t stream) {
    const float* x = (const float*)d_in[0];
    const int* ei = (const int*)d_in[1];
    const int* srcE = ei;
    const int* dstE = ei + EE;
    const float* Wl[3] = {(const float*)d_in[2], (const float*)d_in[8], (const float*)d_in[14]};
    const float* asl[3] = {(const float*)d_in[3], (const float*)d_in[9], (const float*)d_in[15]};
    const float* adl[3] = {(const float*)d_in[4], (const float*)d_in[10], (const float*)d_in[16]};
    const float* bl[3] = {(const float*)d_in[5], (const float*)d_in[11], (const float*)d_in[17]};
    const float* gl[3] = {(const float*)d_in[6], (const float*)d_in[12], (const float*)d_in[18]};
    const float* btl[3] = {(const float*)d_in[7], (const float*)d_in[13], (const float*)d_in[19]};
    const float* fcW = (const float*)d_in[20];
    const float* fcb = (const float*)d_in[21];
    float* out = (float*)d_out;

    // workspace layout (16B-aligned slices)
    char* w = (char*)d_ws;
    float* bufA = (float*)w;            w += (size_t)NN * 96 * 4;   // GEMM output h
    float* bufB = (float*)w;            w += (size_t)NN * 96 * 4;   // aggregated (pre-BN)
    float* alpha_s = (float*)w;         w += (size_t)NN * 4 * 4;
    float* alpha_d = (float*)w;         w += (size_t)NN * 4 * 4;
    float* bn_accum = (float*)w;        w += 192 * 4;               // + amaxU contiguous
    unsigned* amaxU = (unsigned*)w;     w += 4 * 4;
    float* bn_ss = (float*)w;           w += 192 * 4;
    int* row_off = (int*)w;             w += (size_t)(NN + 4) * 4;
    int* cnt = (int*)w;                 w += (size_t)NN * 4;
    int* spart = (int*)w;               w += 256 * 4;
    int* col_src = (int*)w;             w += (size_t)EE * 4;

    // ---- CSR build (per call; ws is re-poisoned every launch) ----
    hipMemsetAsync(cnt, 0, (size_t)NN * 4, stream);
    count_deg_kernel<<<(EE + 255) / 256, 256, 0, stream>>>(dstE, cnt);
    scan_part_kernel<<<NPART, 256, 0, stream>>>(cnt, spart);
    scan_partsum_kernel<<<1, 256, 0, stream>>>(spart);
    scan_final_kernel<<<NPART, 256, 0, stream>>>(cnt, spart, row_off);
    scatter_kernel<<<(EE + 255) / 256, 256, 0, stream>>>(srcE, dstE, row_off, cnt, col_src);

    for (int l = 0; l < 3; l++) {
        hipMemsetAsync(bn_accum, 0, 196 * 4, stream);  // bn_accum + amaxU
        if (l == 0)
            gemm_kernel<128, false><<<(NN + 31) / 32, 256, 0, stream>>>(
                x, Wl[l], asl[l], adl[l], nullptr, bufA, alpha_s, alpha_d, amaxU);
        else
            gemm_kernel<96, true><<<(NN + 31) / 32, 256, 0, stream>>>(
                bufB, Wl[l], asl[l], adl[l], bn_ss, bufA, alpha_s, alpha_d, amaxU);
        agg_kernel<<<(NN + 3) / 4, 256, 0, stream>>>(bufA, alpha_s, alpha_d, amaxU, row_off,
                                                     col_src, bl[l], bufB);
        bn_stats_kernel<<<512, 192, 0, stream>>>(bufB, bn_accum);
        bn_final_kernel<<<1, 128, 0, stream>>>(bn_accum, gl[l], btl[l], bn_ss);
    }
    fc_kernel<<<(NN + 31) / 32, 256, 0, stream>>>(bufB, bn_ss, fcW, fcb, out);
}

// Round 11
// 663.794 us; speedup vs baseline: 1.3891x; 1.0701x over previous
//
#include <hip/hip_runtime.h>

#define NN 50000
#define EE 800000
#define HID 96
#define CDIM 24
#define NEG_SLOPE 0.2f
#define BN_EPS 1e-5f
#define NPART 196   // ceil(NN/256)
#define ACST 200    // accum slot stride (floats): 192 stats + 4 amax + pad

__device__ __forceinline__ float lrelu(float x) { return x > 0.f ? x : NEG_SLOPE * x; }
__device__ __forceinline__ float elu(float x) { return x > 0.f ? x : expm1f(x); }
__device__ __forceinline__ float sel4(float4 v, int h) {
    return (h & 2) ? ((h & 1) ? v.w : v.z) : ((h & 1) ? v.y : v.x);
}
// order-preserving float<->uint for atomicMax; 0 == below all encodings
__device__ __forceinline__ unsigned fenc(float f) {
    unsigned b = __float_as_uint(f);
    return (b & 0x80000000u) ? ~b : (b | 0x80000000u);
}
__device__ __forceinline__ float fdec(unsigned u) {
    return (u & 0x80000000u) ? __uint_as_float(u & 0x7FFFFFFFu) : __uint_as_float(~u);
}

// ---------------- CSR build ----------------
__global__ void count_deg_kernel(const int* __restrict__ dst, int* __restrict__ cnt,
                                 float* __restrict__ accumBase) {
    int i = blockIdx.x * 256 + threadIdx.x;
    if (blockIdx.x == 0 && threadIdx.x < 2 * ACST) accumBase[threadIdx.x] = 0.f;
    if (i < EE) atomicAdd(&cnt[dst[i]], 1);
}

__global__ __launch_bounds__(256) void scan_part_kernel(const int* __restrict__ cnt,
                                                        int* __restrict__ part) {
    int t = threadIdx.x;
    int i = blockIdx.x * 256 + t;
    int v = (i < NN) ? cnt[i] : 0;
#pragma unroll
    for (int off = 1; off < 64; off <<= 1) v += __shfl_xor(v, off);
    __shared__ int ws[4];
    if ((t & 63) == 0) ws[t >> 6] = v;
    __syncthreads();
    if (t == 0) part[blockIdx.x] = ws[0] + ws[1] + ws[2] + ws[3];
}

// final scan; each block redundantly prefixes the raw per-block sums
__global__ __launch_bounds__(256) void scan_final_kernel(const int* __restrict__ cnt,
                                                         const int* __restrict__ part,
                                                         int* __restrict__ row_off) {
    int t = threadIdx.x;
    __shared__ int pre_s;
    __shared__ int wsum[4];
    if (t < 64) {
        int acc = 0;
        for (int j = t; j < blockIdx.x; j += 64) acc += part[j];
#pragma unroll
        for (int off = 1; off < 64; off <<= 1) acc += __shfl_xor(acc, off);
        if (t == 0) pre_s = acc;
    }
    __syncthreads();
    int i = blockIdx.x * 256 + t;
    int lane = t & 63, wv = t >> 6;
    int v = (i < NN) ? cnt[i] : 0;
    int x = v;
#pragma unroll
    for (int off = 1; off < 64; off <<= 1) {
        int y = __shfl_up(x, off);
        if (lane >= off) x += y;
    }
    if (lane == 63) wsum[wv] = x;
    __syncthreads();
    int wb = 0;
    for (int j = 0; j < wv; j++) wb += wsum[j];
    if (i < NN) row_off[i] = pre_s + wb + x - v;
    if (i == NN) row_off[NN] = EE;
}

__global__ void scatter_kernel(const int* __restrict__ src, const int* __restrict__ dst,
                               const int* __restrict__ row_off, int* __restrict__ cnt,
                               int* __restrict__ col_src) {
    int i = blockIdx.x * 256 + threadIdx.x;
    if (i < EE) {
        int d = dst[i];
        int pos = atomicSub(&cnt[d], 1) - 1;
        col_src[row_off[d] + pos] = src[i];
    }
}

// ---------------- GEMM: H = X @ W, fused BN+ELU (inline scale/shift from raw
// stats), fused alpha logits + global As-max. 256 thr = 8 col-groups(12 cols,
// float4-aligned) x 32 row-slots; thread owns rows {rs, rs+32}.
template <int K, bool BN>
__global__ __launch_bounds__(256) void gemm_kernel(const float* __restrict__ X,
                                                   const float* __restrict__ W,
                                                   const float* __restrict__ a_s,
                                                   const float* __restrict__ a_d,
                                                   const float* __restrict__ accumPrev,
                                                   const float* __restrict__ gam,
                                                   const float* __restrict__ bet,
                                                   float* __restrict__ H,
                                                   float* __restrict__ As,
                                                   float* __restrict__ Ad,
                                                   unsigned* __restrict__ amaxU) {
    const int KC = 32;
    __shared__ float Ws[KC * 96];       // 12 KB
    __shared__ float Xs[64][KC + 4];    // 9.2 KB, stride 36 (quads aligned)
    __shared__ float ssl[192];
    __shared__ unsigned amx[4];
    int t = threadIdx.x;
    if (t < 4) amx[t] = 0u;
    if (BN && t < 96) {
        float mean = accumPrev[t] * (1.0f / NN);
        float var = accumPrev[96 + t] * (1.0f / NN) - mean * mean;
        float sc = gam[t] * rsqrtf(var + BN_EPS);
        ssl[t] = sc;
        ssl[96 + t] = bet[t] - mean * sc;
    }
    if (BN) __syncthreads();
    int row0 = blockIdx.x * 64;
    int grp = t & 7, rs = t >> 3;
    int c0 = grp * 12;
    float accA[12], accB[12];
#pragma unroll
    for (int j = 0; j < 12; j++) { accA[j] = 0.f; accB[j] = 0.f; }
    for (int k0 = 0; k0 < K; k0 += KC) {
        for (int i = t; i < KC * 24; i += 256)
            ((float4*)Ws)[i] = ((const float4*)(W + (size_t)k0 * 96))[i];
        for (int i = t; i < 64 * (KC / 4); i += 256) {
            int lr = i >> 3, q = i & 7;
            float4 v = make_float4(0.f, 0.f, 0.f, 0.f);
            if (row0 + lr < NN) {
                v = *(const float4*)(X + (size_t)(row0 + lr) * K + k0 + q * 4);
                if (BN) {
                    int f = k0 + q * 4;
                    v.x = elu(v.x * ssl[f + 0] + ssl[96 + f + 0]);
                    v.y = elu(v.y * ssl[f + 1] + ssl[96 + f + 1]);
                    v.z = elu(v.z * ssl[f + 2] + ssl[96 + f + 2]);
                    v.w = elu(v.w * ssl[f + 3] + ssl[96 + f + 3]);
                }
            }
            *(float4*)(&Xs[lr][q * 4]) = v;
        }
        __syncthreads();
#pragma unroll
        for (int k = 0; k < KC; k++) {
            float va = Xs[rs][k];
            float vb = Xs[rs + 32][k];
            const float4* wr = (const float4*)(&Ws[k * 96 + c0]);
            float4 w0 = wr[0], w1 = wr[1], w2 = wr[2];
            accA[0] += va * w0.x; accA[1] += va * w0.y; accA[2] += va * w0.z; accA[3] += va * w0.w;
            accA[4] += va * w1.x; accA[5] += va * w1.y; accA[6] += va * w1.z; accA[7] += va * w1.w;
            accA[8] += va * w2.x; accA[9] += va * w2.y; accA[10] += va * w2.z; accA[11] += va * w2.w;
            accB[0] += vb * w0.x; accB[1] += vb * w0.y; accB[2] += vb * w0.z; accB[3] += vb * w0.w;
            accB[4] += vb * w1.x; accB[5] += vb * w1.y; accB[6] += vb * w1.z; accB[7] += vb * w1.w;
            accB[8] += vb * w2.x; accB[9] += vb * w2.y; accB[10] += vb * w2.z; accB[11] += vb * w2.w;
        }
        __syncthreads();
    }
    int gA = row0 + rs, gB = row0 + 32 + rs;
    bool vA = gA < NN, vB = gB < NN;
    if (vA) {
        float* o = H + (size_t)gA * 96 + c0;
        *(float4*)(o + 0) = make_float4(accA[0], accA[1], accA[2], accA[3]);
        *(float4*)(o + 4) = make_float4(accA[4], accA[5], accA[6], accA[7]);
        *(float4*)(o + 8) = make_float4(accA[8], accA[9], accA[10], accA[11]);
    }
    if (vB) {
        float* o = H + (size_t)gB * 96 + c0;
        *(float4*)(o + 0) = make_float4(accB[0], accB[1], accB[2], accB[3]);
        *(float4*)(o + 4) = make_float4(accB[4], accB[5], accB[6], accB[7]);
        *(float4*)(o + 8) = make_float4(accB[8], accB[9], accB[10], accB[11]);
    }
    // alpha logits: 12 cols lie within one head (12 | 24); pair-reduce lanes g,g^1
    float psA = 0.f, pdA = 0.f, psB = 0.f, pdB = 0.f;
#pragma unroll
    for (int j = 0; j < 12; j++) {
        float av = a_s[c0 + j], dv = a_d[c0 + j];
        psA += accA[j] * av; pdA += accA[j] * dv;
        psB += accB[j] * av; pdB += accB[j] * dv;
    }
    psA += __shfl_xor(psA, 1); pdA += __shfl_xor(pdA, 1);
    psB += __shfl_xor(psB, 1); pdB += __shfl_xor(pdB, 1);
    int hh = grp >> 1;
    if ((t & 1) == 0) {
        if (vA) { As[gA * 4 + hh] = psA; Ad[gA * 4 + hh] = pdA; }
        if (vB) { As[gB * 4 + hh] = psB; Ad[gB * 4 + hh] = pdB; }
    }
    // per-head global max of As (upper bound for softmax stabilizer)
    float pm = vA ? psA : -3.4e38f;
    if (vB) pm = fmaxf(pm, psB);
    pm = fmaxf(pm, __shfl_xor(pm, 1));
    pm = fmaxf(pm, __shfl_xor(pm, 8));
    pm = fmaxf(pm, __shfl_xor(pm, 16));
    pm = fmaxf(pm, __shfl_xor(pm, 32));
    if ((t & 57) == 0) atomicMax(&amx[hh], fenc(pm));  // bits 0,3,4,5 clear
    __syncthreads();
    if (t < 4) atomicMax(&amaxU[t], amx[t]);
}

// ---------------- aggregation: wave/node, 48 lanes x float2 features ---------
__global__ __launch_bounds__(256) void agg_kernel(const float* __restrict__ H,
                                                  const float* __restrict__ As,
                                                  const float* __restrict__ Ad,
                                                  const unsigned* __restrict__ Mu,
                                                  const int* __restrict__ row_off,
                                                  const int* __restrict__ col_src,
                                                  const float* __restrict__ bias,
                                                  float* __restrict__ out) {
    int wave = threadIdx.x >> 6;
    int lane = threadIdx.x & 63;
    int n = blockIdx.x * 4 + wave;
    if (lane >= 48) return;          // features {2*lane, 2*lane+1}
    int h = lane / 12;               // head = (2*lane)/24
    const float4* As4 = (const float4*)As;
    const float2* H2 = (const float2*)H;
    float4 adv = ((const float4*)Ad)[n];
    float ad_h = sel4(adv, h);
    float m = lrelu(fdec(Mu[h]) + ad_h);
    int beg = row_off[n], end = row_off[n + 1];

    float s1 = 0.f;
    float2 acc = {0.f, 0.f};
    {   // self-loop
        float4 a = As4[n];
        float p = __expf(lrelu(sel4(a, h) + ad_h) - m);
        float2 hv = H2[(size_t)n * 48 + lane];
        s1 += p;
        acc.x += p * hv.x; acc.y += p * hv.y;
    }
    int e = beg;
    for (; e + 4 <= end; e += 4) {
        int sa = col_src[e], sb = col_src[e + 1], sc = col_src[e + 2], sd = col_src[e + 3];
        float4 a0 = As4[sa], a1 = As4[sb], a2 = As4[sc], a3 = As4[sd];
        float2 h0 = H2[(size_t)sa * 48 + lane];
        float2 h1 = H2[(size_t)sb * 48 + lane];
        float2 h2v = H2[(size_t)sc * 48 + lane];
        float2 h3 = H2[(size_t)sd * 48 + lane];
        float p0 = __expf(lrelu(sel4(a0, h) + ad_h) - m);
        float p1 = __expf(lrelu(sel4(a1, h) + ad_h) - m);
        float p2 = __expf(lrelu(sel4(a2, h) + ad_h) - m);
        float p3 = __expf(lrelu(sel4(a3, h) + ad_h) - m);
        s1 += p0; s1 += p1; s1 += p2; s1 += p3;
        acc.x += p0 * h0.x; acc.y += p0 * h0.y;
        acc.x += p1 * h1.x; acc.y += p1 * h1.y;
        acc.x += p2 * h2v.x; acc.y += p2 * h2v.y;
        acc.x += p3 * h3.x; acc.y += p3 * h3.y;
    }
    for (; e < end; e++) {
        int s = col_src[e];
        float4 a = As4[s];
        float p = __expf(lrelu(sel4(a, h) + ad_h) - m);
        float2 hv = H2[(size_t)s * 48 + lane];
        s1 += p;
        acc.x += p * hv.x; acc.y += p * hv.y;
    }
    float inv = 1.f / (s1 + 1e-16f);
    float2 b2 = ((const float2*)bias)[lane];
    float2 o;
    o.x = acc.x * inv + b2.x;
    o.y = acc.y * inv + b2.y;
    ((float2*)out)[(size_t)n * 48 + lane] = o;
}

// ---------------- BatchNorm stats; also zeros the OTHER slot for next layer --
__global__ __launch_bounds__(192) void bn_stats_kernel(const float* __restrict__ Y,
                                                       float* __restrict__ accum,
                                                       float* __restrict__ other) {
    int t = threadIdx.x;
    int zi = blockIdx.x * 192 + t;
    if (zi < ACST) other[zi] = 0.f;  // blocks 0-1 zero the ping-pong slot
    float4 s = {0.f, 0.f, 0.f, 0.f}, q = {0.f, 0.f, 0.f, 0.f};
    for (int i4 = blockIdx.x * 192 + t; i4 < NN * 24; i4 += 512 * 192) {
        float4 v = ((const float4*)Y)[i4];
        s.x += v.x; s.y += v.y; s.z += v.z; s.w += v.w;
        q.x += v.x * v.x; q.y += v.y * v.y; q.z += v.z * v.z; q.w += v.w * v.w;
    }
    __shared__ float4 ls[192], lq[192];
    ls[t] = s;
    lq[t] = q;
    __syncthreads();
    if (t < 24) {
        float4 S = ls[t], Q = lq[t];
        for (int i = 1; i < 8; i++) {
            float4 a = ls[t + 24 * i], b = lq[t + 24 * i];
            S.x += a.x; S.y += a.y; S.z += a.z; S.w += a.w;
            Q.x += b.x; Q.y += b.y; Q.z += b.z; Q.w += b.w;
        }
        int f = t * 4;
        atomicAdd(&accum[f + 0], S.x); atomicAdd(&accum[f + 1], S.y);
        atomicAdd(&accum[f + 2], S.z); atomicAdd(&accum[f + 3], S.w);
        atomicAdd(&accum[96 + f + 0], Q.x); atomicAdd(&accum[96 + f + 1], Q.y);
        atomicAdd(&accum[96 + f + 2], Q.z); atomicAdd(&accum[96 + f + 3], Q.w);
    }
}

// ---------------- final FC with inline BN+ELU from raw stats -----------------
__global__ __launch_bounds__(256) void fc_kernel(const float* __restrict__ Y,
                                                 const float* __restrict__ accumPrev,
                                                 const float* __restrict__ gam,
                                                 const float* __restrict__ bet,
                                                 const float* __restrict__ W,
                                                 const float* __restrict__ b,
                                                 float* __restrict__ out) {
    __shared__ float w[96 * 8];
    __shared__ float yl[32][100];
    __shared__ float ssl[192];
    __shared__ float bb[8];
    int t = threadIdx.x;
    if (t < 96) {
        float mean = accumPrev[t] * (1.0f / NN);
        float var = accumPrev[96 + t] * (1.0f / NN) - mean * mean;
        float sc = gam[t] * rsqrtf(var + BN_EPS);
        ssl[t] = sc;
        ssl[96 + t] = bet[t] - mean * sc;
    }
    for (int i = t; i < 768; i += 256) w[i] = W[i];
    if (t < 8) bb[t] = b[t];
    __syncthreads();
    int row0 = blockIdx.x * 32;
    for (int i = t; i < 768; i += 256) {  // 32 rows x 24 quads
        int lr = i / 24, q = i % 24;
        float4 v = make_float4(0.f, 0.f, 0.f, 0.f);
        if (row0 + lr < NN) {
            v = *(const float4*)(Y + (size_t)(row0 + lr) * 96 + q * 4);
            int f = q * 4;
            v.x = elu(v.x * ssl[f + 0] + ssl[96 + f + 0]);
            v.y = elu(v.y * ssl[f + 1] + ssl[96 + f + 1]);
            v.z = elu(v.z * ssl[f + 2] + ssl[96 + f + 2]);
            v.w = elu(v.w * ssl[f + 3] + ssl[96 + f + 3]);
        }
        *(float4*)(&yl[lr][q * 4]) = v;
    }
    __syncthreads();
    int ln = t >> 3;
    int cl = t & 7;
    int n = row0 + ln;
    if (n >= NN) return;
    float acc = bb[cl];
#pragma unroll 8
    for (int k = 0; k < 96; k++) acc += yl[ln][k] * w[k * 8 + cl];
    out[(size_t)n * 8 + cl] = acc;
}

extern "C" void kernel_launch(void* const* d_in, const int* in_sizes, int n_in,
                              void* d_out, int out_size, void* d_ws, size_t ws_size,
                              hipStream_t stream) {
    const float* x = (const float*)d_in[0];
    const int* ei = (const int*)d_in[1];
    const int* srcE = ei;
    const int* dstE = ei + EE;
    const float* Wl[3] = {(const float*)d_in[2], (const float*)d_in[8], (const float*)d_in[14]};
    const float* asl[3] = {(const float*)d_in[3], (const float*)d_in[9], (const float*)d_in[15]};
    const float* adl[3] = {(const float*)d_in[4], (const float*)d_in[10], (const float*)d_in[16]};
    const float* bl[3] = {(const float*)d_in[5], (const float*)d_in[11], (const float*)d_in[17]};
    const float* gl[3] = {(const float*)d_in[6], (const float*)d_in[12], (const float*)d_in[18]};
    const float* btl[3] = {(const float*)d_in[7], (const float*)d_in[13], (const float*)d_in[19]};
    const float* fcW = (const float*)d_in[20];
    const float* fcb = (const float*)d_in[21];
    float* out = (float*)d_out;

    char* w = (char*)d_ws;
    float* bufA = (float*)w;        w += (size_t)NN * 96 * 4;
    float* bufB = (float*)w;        w += (size_t)NN * 96 * 4;
    float* alpha_s = (float*)w;     w += (size_t)NN * 4 * 4;
    float* alpha_d = (float*)w;     w += (size_t)NN * 4 * 4;
    float* accumBase = (float*)w;   w += 2 * ACST * 4;   // 2 slots: 192 stats + 4 amax
    int* row_off = (int*)w;         w += (size_t)(NN + 4) * 4;
    int* cnt = (int*)w;             w += (size_t)NN * 4;
    int* spart = (int*)w;           w += 256 * 4;
    int* col_src = (int*)w;         w += (size_t)EE * 4;

    float* slot[2] = {accumBase, accumBase + ACST};
    unsigned* amax[2] = {(unsigned*)(accumBase + 192), (unsigned*)(accumBase + ACST + 192)};

    // ---- CSR build ----
    hipMemsetAsync(cnt, 0, (size_t)NN * 4, stream);
    count_deg_kernel<<<(EE + 255) / 256, 256, 0, stream>>>(dstE, cnt, accumBase);
    scan_part_kernel<<<NPART, 256, 0, stream>>>(cnt, spart);
    scan_final_kernel<<<NPART, 256, 0, stream>>>(cnt, spart, row_off);
    scatter_kernel<<<(EE + 255) / 256, 256, 0, stream>>>(srcE, dstE, row_off, cnt, col_src);

    for (int l = 0; l < 3; l++) {
        int sl = l & 1, so = (l + 1) & 1;
        if (l == 0)
            gemm_kernel<128, false><<<(NN + 63) / 64, 256, 0, stream>>>(
                x, Wl[0], asl[0], adl[0], nullptr, nullptr, nullptr,
                bufA, alpha_s, alpha_d, amax[0]);
        else
            gemm_kernel<96, true><<<(NN + 63) / 64, 256, 0, stream>>>(
                bufB, Wl[l], asl[l], adl[l], slot[so], gl[l - 1], btl[l - 1],
                bufA, alpha_s, alpha_d, amax[sl]);
        agg_kernel<<<(NN + 3) / 4, 256, 0, stream>>>(bufA, alpha_s, alpha_d, amax[sl],
                                                     row_off, col_src, bl[l], bufB);
        bn_stats_kernel<<<512, 192, 0, stream>>>(bufB, slot[sl], slot[so]);
    }
    fc_kernel<<<(NN + 31) / 32, 256, 0, stream>>>(bufB, slot[0], gl[2], btl[2], fcW, fcb, out);
}

// Round 13
// 630.466 us; speedup vs baseline: 1.4625x; 1.0529x over previous
//
#include <hip/hip_runtime.h>

#define NN 50000
#define EE 800000
#define HID 96
#define CDIM 24
#define NEG_SLOPE 0.2f
#define BN_EPS 1e-5f
#define NPART 196   // ceil(NN/256)
#define ACST 200    // accum slot stride (floats): 192 stats + 4 amax + pad
#define BNB 1024    // bn_stats stage-A blocks

__device__ __forceinline__ float lrelu(float x) { return x > 0.f ? x : NEG_SLOPE * x; }
__device__ __forceinline__ float elu(float x) { return x > 0.f ? x : expm1f(x); }
__device__ __forceinline__ float sel4(float4 v, int h) {
    return (h & 2) ? ((h & 1) ? v.w : v.z) : ((h & 1) ? v.y : v.x);
}
// order-preserving float<->uint for atomicMax; 0 == below all encodings
__device__ __forceinline__ unsigned fenc(float f) {
    unsigned b = __float_as_uint(f);
    return (b & 0x80000000u) ? ~b : (b | 0x80000000u);
}
__device__ __forceinline__ float fdec(unsigned u) {
    return (u & 0x80000000u) ? __uint_as_float(u & 0x7FFFFFFFu) : __uint_as_float(~u);
}

// ---------------- CSR build ----------------
__global__ void count_deg_kernel(const int* __restrict__ dst, int* __restrict__ cnt,
                                 float* __restrict__ accumBase) {
    int i = blockIdx.x * 256 + threadIdx.x;
    if (blockIdx.x == 0 && threadIdx.x < 2 * ACST) accumBase[threadIdx.x] = 0.f;
    if (i < EE) atomicAdd(&cnt[dst[i]], 1);
}

__global__ __launch_bounds__(256) void scan_part_kernel(const int* __restrict__ cnt,
                                                        int* __restrict__ part) {
    int t = threadIdx.x;
    int i = blockIdx.x * 256 + t;
    int v = (i < NN) ? cnt[i] : 0;
#pragma unroll
    for (int off = 1; off < 64; off <<= 1) v += __shfl_xor(v, off);
    __shared__ int ws[4];
    if ((t & 63) == 0) ws[t >> 6] = v;
    __syncthreads();
    if (t == 0) part[blockIdx.x] = ws[0] + ws[1] + ws[2] + ws[3];
}

// final scan; each block redundantly prefixes the raw per-block sums
__global__ __launch_bounds__(256) void scan_final_kernel(const int* __restrict__ cnt,
                                                         const int* __restrict__ part,
                                                         int* __restrict__ row_off) {
    int t = threadIdx.x;
    __shared__ int pre_s;
    __shared__ int wsum[4];
    if (t < 64) {
        int acc = 0;
        for (int j = t; j < blockIdx.x; j += 64) acc += part[j];
#pragma unroll
        for (int off = 1; off < 64; off <<= 1) acc += __shfl_xor(acc, off);
        if (t == 0) pre_s = acc;
    }
    __syncthreads();
    int i = blockIdx.x * 256 + t;
    int lane = t & 63, wv = t >> 6;
    int v = (i < NN) ? cnt[i] : 0;
    int x = v;
#pragma unroll
    for (int off = 1; off < 64; off <<= 1) {
        int y = __shfl_up(x, off);
        if (lane >= off) x += y;
    }
    if (lane == 63) wsum[wv] = x;
    __syncthreads();
    int wb = 0;
    for (int j = 0; j < wv; j++) wb += wsum[j];
    if (i < NN) row_off[i] = pre_s + wb + x - v;
    if (i == NN) row_off[NN] = EE;
}

__global__ void scatter_kernel(const int* __restrict__ src, const int* __restrict__ dst,
                               const int* __restrict__ row_off, int* __restrict__ cnt,
                               int* __restrict__ col_src) {
    int i = blockIdx.x * 256 + threadIdx.x;
    if (i < EE) {
        int d = dst[i];
        int pos = atomicSub(&cnt[d], 1) - 1;
        col_src[row_off[d] + pos] = src[i];
    }
}

// ---------------- GEMM: H = X @ W, fused BN+ELU (inline scale/shift from raw
// stats), fused alpha logits + global As-max. 256 thr = 8 col-groups(12 cols,
// float4-aligned) x 32 row-slots; thread owns rows {rs, rs+32}.
template <int K, bool BN>
__global__ __launch_bounds__(256) void gemm_kernel(const float* __restrict__ X,
                                                   const float* __restrict__ W,
                                                   const float* __restrict__ a_s,
                                                   const float* __restrict__ a_d,
                                                   const float* __restrict__ accumPrev,
                                                   const float* __restrict__ gam,
                                                   const float* __restrict__ bet,
                                                   float* __restrict__ H,
                                                   float* __restrict__ As,
                                                   float* __restrict__ Ad,
                                                   unsigned* __restrict__ amaxU) {
    const int KC = 32;
    __shared__ float Ws[KC * 96];       // 12 KB
    __shared__ float Xs[64][KC + 4];    // 9.2 KB, stride 36 (quads aligned)
    __shared__ float ssl[192];
    __shared__ unsigned amx[4];
    int t = threadIdx.x;
    if (t < 4) amx[t] = 0u;
    if (BN && t < 96) {
        float mean = accumPrev[t] * (1.0f / NN);
        float var = accumPrev[96 + t] * (1.0f / NN) - mean * mean;
        float sc = gam[t] * rsqrtf(var + BN_EPS);
        ssl[t] = sc;
        ssl[96 + t] = bet[t] - mean * sc;
    }
    if (BN) __syncthreads();
    int row0 = blockIdx.x * 64;
    int grp = t & 7, rs = t >> 3;
    int c0 = grp * 12;
    float accA[12], accB[12];
#pragma unroll
    for (int j = 0; j < 12; j++) { accA[j] = 0.f; accB[j] = 0.f; }
    for (int k0 = 0; k0 < K; k0 += KC) {
        for (int i = t; i < KC * 24; i += 256)
            ((float4*)Ws)[i] = ((const float4*)(W + (size_t)k0 * 96))[i];
        for (int i = t; i < 64 * (KC / 4); i += 256) {
            int lr = i >> 3, q = i & 7;
            float4 v = make_float4(0.f, 0.f, 0.f, 0.f);
            if (row0 + lr < NN) {
                v = *(const float4*)(X + (size_t)(row0 + lr) * K + k0 + q * 4);
                if (BN) {
                    int f = k0 + q * 4;
                    v.x = elu(v.x * ssl[f + 0] + ssl[96 + f + 0]);
                    v.y = elu(v.y * ssl[f + 1] + ssl[96 + f + 1]);
                    v.z = elu(v.z * ssl[f + 2] + ssl[96 + f + 2]);
                    v.w = elu(v.w * ssl[f + 3] + ssl[96 + f + 3]);
                }
            }
            *(float4*)(&Xs[lr][q * 4]) = v;
        }
        __syncthreads();
#pragma unroll
        for (int k = 0; k < KC; k++) {
            float va = Xs[rs][k];
            float vb = Xs[rs + 32][k];
            const float4* wr = (const float4*)(&Ws[k * 96 + c0]);
            float4 w0 = wr[0], w1 = wr[1], w2 = wr[2];
            accA[0] += va * w0.x; accA[1] += va * w0.y; accA[2] += va * w0.z; accA[3] += va * w0.w;
            accA[4] += va * w1.x; accA[5] += va * w1.y; accA[6] += va * w1.z; accA[7] += va * w1.w;
            accA[8] += va * w2.x; accA[9] += va * w2.y; accA[10] += va * w2.z; accA[11] += va * w2.w;
            accB[0] += vb * w0.x; accB[1] += vb * w0.y; accB[2] += vb * w0.z; accB[3] += vb * w0.w;
            accB[4] += vb * w1.x; accB[5] += vb * w1.y; accB[6] += vb * w1.z; accB[7] += vb * w1.w;
            accB[8] += vb * w2.x; accB[9] += vb * w2.y; accB[10] += vb * w2.z; accB[11] += vb * w2.w;
        }
        __syncthreads();
    }
    int gA = row0 + rs, gB = row0 + 32 + rs;
    bool vA = gA < NN, vB = gB < NN;
    if (vA) {
        float* o = H + (size_t)gA * 96 + c0;
        *(float4*)(o + 0) = make_float4(accA[0], accA[1], accA[2], accA[3]);
        *(float4*)(o + 4) = make_float4(accA[4], accA[5], accA[6], accA[7]);
        *(float4*)(o + 8) = make_float4(accA[8], accA[9], accA[10], accA[11]);
    }
    if (vB) {
        float* o = H + (size_t)gB * 96 + c0;
        *(float4*)(o + 0) = make_float4(accB[0], accB[1], accB[2], accB[3]);
        *(float4*)(o + 4) = make_float4(accB[4], accB[5], accB[6], accB[7]);
        *(float4*)(o + 8) = make_float4(accB[8], accB[9], accB[10], accB[11]);
    }
    // alpha logits: 12 cols lie within one head (12 | 24); pair-reduce lanes g,g^1
    float psA = 0.f, pdA = 0.f, psB = 0.f, pdB = 0.f;
#pragma unroll
    for (int j = 0; j < 12; j++) {
        float av = a_s[c0 + j], dv = a_d[c0 + j];
        psA += accA[j] * av; pdA += accA[j] * dv;
        psB += accB[j] * av; pdB += accB[j] * dv;
    }
    psA += __shfl_xor(psA, 1); pdA += __shfl_xor(pdA, 1);
    psB += __shfl_xor(psB, 1); pdB += __shfl_xor(pdB, 1);
    int hh = grp >> 1;
    if ((t & 1) == 0) {
        if (vA) { As[gA * 4 + hh] = psA; Ad[gA * 4 + hh] = pdA; }
        if (vB) { As[gB * 4 + hh] = psB; Ad[gB * 4 + hh] = pdB; }
    }
    // per-head global max of As (upper bound for softmax stabilizer)
    float pm = vA ? psA : -3.4e38f;
    if (vB) pm = fmaxf(pm, psB);
    pm = fmaxf(pm, __shfl_xor(pm, 1));
    pm = fmaxf(pm, __shfl_xor(pm, 8));
    pm = fmaxf(pm, __shfl_xor(pm, 16));
    pm = fmaxf(pm, __shfl_xor(pm, 32));
    if ((t & 57) == 0) atomicMax(&amx[hh], fenc(pm));  // bits 0,3,4,5 clear
    __syncthreads();
    if (t < 4) atomicMax(&amaxU[t], amx[t]);
}

// ---------------- aggregation: wave/node, 48 lanes x float2 features ---------
__global__ __launch_bounds__(256) void agg_kernel(const float* __restrict__ H,
                                                  const float* __restrict__ As,
                                                  const float* __restrict__ Ad,
                                                  const unsigned* __restrict__ Mu,
                                                  const int* __restrict__ row_off,
                                                  const int* __restrict__ col_src,
                                                  const float* __restrict__ bias,
                                                  float* __restrict__ out) {
    int wave = threadIdx.x >> 6;
    int lane = threadIdx.x & 63;
    int n = blockIdx.x * 4 + wave;
    if (lane >= 48) return;          // features {2*lane, 2*lane+1}
    int h = lane / 12;               // head = (2*lane)/24
    const float4* As4 = (const float4*)As;
    const float2* H2 = (const float2*)H;
    float4 adv = ((const float4*)Ad)[n];
    float ad_h = sel4(adv, h);
    float m = lrelu(fdec(Mu[h]) + ad_h);
    int beg = row_off[n], end = row_off[n + 1];

    float s1 = 0.f;
    float2 acc = {0.f, 0.f};
    {   // self-loop
        float4 a = As4[n];
        float p = __expf(lrelu(sel4(a, h) + ad_h) - m);
        float2 hv = H2[(size_t)n * 48 + lane];
        s1 += p;
        acc.x += p * hv.x; acc.y += p * hv.y;
    }
    int e = beg;
    for (; e + 4 <= end; e += 4) {
        int sa = col_src[e], sb = col_src[e + 1], sc = col_src[e + 2], sd = col_src[e + 3];
        float4 a0 = As4[sa], a1 = As4[sb], a2 = As4[sc], a3 = As4[sd];
        float2 h0 = H2[(size_t)sa * 48 + lane];
        float2 h1 = H2[(size_t)sb * 48 + lane];
        float2 h2v = H2[(size_t)sc * 48 + lane];
        float2 h3 = H2[(size_t)sd * 48 + lane];
        float p0 = __expf(lrelu(sel4(a0, h) + ad_h) - m);
        float p1 = __expf(lrelu(sel4(a1, h) + ad_h) - m);
        float p2 = __expf(lrelu(sel4(a2, h) + ad_h) - m);
        float p3 = __expf(lrelu(sel4(a3, h) + ad_h) - m);
        s1 += p0; s1 += p1; s1 += p2; s1 += p3;
        acc.x += p0 * h0.x; acc.y += p0 * h0.y;
        acc.x += p1 * h1.x; acc.y += p1 * h1.y;
        acc.x += p2 * h2v.x; acc.y += p2 * h2v.y;
        acc.x += p3 * h3.x; acc.y += p3 * h3.y;
    }
    for (; e < end; e++) {
        int s = col_src[e];
        float4 a = As4[s];
        float p = __expf(lrelu(sel4(a, h) + ad_h) - m);
        float2 hv = H2[(size_t)s * 48 + lane];
        s1 += p;
        acc.x += p * hv.x; acc.y += p * hv.y;
    }
    float inv = 1.f / (s1 + 1e-16f);
    float2 b2 = ((const float2*)bias)[lane];
    float2 o;
    o.x = acc.x * inv + b2.x;
    o.y = acc.y * inv + b2.y;
    ((float2*)out)[(size_t)n * 48 + lane] = o;
}

// ---------------- BatchNorm stats stage A: per-block partials, NO atomics ----
__global__ __launch_bounds__(192) void bn_stats_kernel(const float* __restrict__ Y,
                                                       float* __restrict__ part) {
    int t = threadIdx.x;
    float4 s = {0.f, 0.f, 0.f, 0.f}, q = {0.f, 0.f, 0.f, 0.f};
    // stride BNB*192 quads ≡ 0 (mod 24) -> feature quad fixed per thread
#pragma unroll 4
    for (int i4 = blockIdx.x * 192 + t; i4 < NN * 24; i4 += BNB * 192) {
        float4 v = ((const float4*)Y)[i4];
        s.x += v.x; s.y += v.y; s.z += v.z; s.w += v.w;
        q.x += v.x * v.x; q.y += v.y * v.y; q.z += v.z * v.z; q.w += v.w * v.w;
    }
    __shared__ float4 ls[192], lq[192];
    ls[t] = s;
    lq[t] = q;
    __syncthreads();
    if (t < 24) {
        float4 S = ls[t], Q = lq[t];
        for (int i = 1; i < 8; i++) {
            float4 a = ls[t + 24 * i], b = lq[t + 24 * i];
            S.x += a.x; S.y += a.y; S.z += a.z; S.w += a.w;
            Q.x += b.x; Q.y += b.y; Q.z += b.z; Q.w += b.w;
        }
        // layout: part[b][0..95]=sum, part[b][96..191]=sumsq
        ((float4*)part)[blockIdx.x * 48 + t] = S;
        ((float4*)part)[blockIdx.x * 48 + 24 + t] = Q;
    }
}

// ---------------- stage B: column-sum the partials; zero other amax slot -----
__global__ __launch_bounds__(256) void bn_reduce_kernel(const float* __restrict__ part,
                                                        float* __restrict__ accum,
                                                        unsigned* __restrict__ amaxOther) {
    int t = threadIdx.x;
    if (t < 192) {
        float a = 0.f;
#pragma unroll 8
        for (int b = 0; b < BNB; b++) a += part[b * 192 + t];
        accum[t] = a;
    } else if (t < 196) {
        amaxOther[t - 192] = 0u;
    }
}

// ---------------- final FC with inline BN+ELU from raw stats -----------------
__global__ __launch_bounds__(256) void fc_kernel(const float* __restrict__ Y,
                                                 const float* __restrict__ accumPrev,
                                                 const float* __restrict__ gam,
                                                 const float* __restrict__ bet,
                                                 const float* __restrict__ W,
                                                 const float* __restrict__ b,
                                                 float* __restrict__ out) {
    __shared__ float w[96 * 8];
    __shared__ float yl[32][100];
    __shared__ float ssl[192];
    __shared__ float bb[8];
    int t = threadIdx.x;
    if (t < 96) {
        float mean = accumPrev[t] * (1.0f / NN);
        float var = accumPrev[96 + t] * (1.0f / NN) - mean * mean;
        float sc = gam[t] * rsqrtf(var + BN_EPS);
        ssl[t] = sc;
        ssl[96 + t] = bet[t] - mean * sc;
    }
    for (int i = t; i < 768; i += 256) w[i] = W[i];
    if (t < 8) bb[t] = b[t];
    __syncthreads();
    int row0 = blockIdx.x * 32;
    for (int i = t; i < 768; i += 256) {  // 32 rows x 24 quads
        int lr = i / 24, q = i % 24;
        float4 v = make_float4(0.f, 0.f, 0.f, 0.f);
        if (row0 + lr < NN) {
            v = *(const float4*)(Y + (size_t)(row0 + lr) * 96 + q * 4);
            int f = q * 4;
            v.x = elu(v.x * ssl[f + 0] + ssl[96 + f + 0]);
            v.y = elu(v.y * ssl[f + 1] + ssl[96 + f + 1]);
            v.z = elu(v.z * ssl[f + 2] + ssl[96 + f + 2]);
            v.w = elu(v.w * ssl[f + 3] + ssl[96 + f + 3]);
        }
        *(float4*)(&yl[lr][q * 4]) = v;
    }
    __syncthreads();
    int ln = t >> 3;
    int cl = t & 7;
    int n = row0 + ln;
    if (n >= NN) return;
    float acc = bb[cl];
#pragma unroll 8
    for (int k = 0; k < 96; k++) acc += yl[ln][k] * w[k * 8 + cl];
    out[(size_t)n * 8 + cl] = acc;
}

extern "C" void kernel_launch(void* const* d_in, const int* in_sizes, int n_in,
                              void* d_out, int out_size, void* d_ws, size_t ws_size,
                              hipStream_t stream) {
    const float* x = (const float*)d_in[0];
    const int* ei = (const int*)d_in[1];
    const int* srcE = ei;
    const int* dstE = ei + EE;
    const float* Wl[3] = {(const float*)d_in[2], (const float*)d_in[8], (const float*)d_in[14]};
    const float* asl[3] = {(const float*)d_in[3], (const float*)d_in[9], (const float*)d_in[15]};
    const float* adl[3] = {(const float*)d_in[4], (const float*)d_in[10], (const float*)d_in[16]};
    const float* bl[3] = {(const float*)d_in[5], (const float*)d_in[11], (const float*)d_in[17]};
    const float* gl[3] = {(const float*)d_in[6], (const float*)d_in[12], (const float*)d_in[18]};
    const float* btl[3] = {(const float*)d_in[7], (const float*)d_in[13], (const float*)d_in[19]};
    const float* fcW = (const float*)d_in[20];
    const float* fcb = (const float*)d_in[21];
    float* out = (float*)d_out;

    char* w = (char*)d_ws;
    float* bufA = (float*)w;        w += (size_t)NN * 96 * 4;
    float* bufB = (float*)w;        w += (size_t)NN * 96 * 4;
    float* alpha_s = (float*)w;     w += (size_t)NN * 4 * 4;
    float* alpha_d = (float*)w;     w += (size_t)NN * 4 * 4;
    float* accumBase = (float*)w;   w += 2 * ACST * 4;   // 2 slots: 192 stats + 4 amax
    float* bnpart = (float*)w;      w += (size_t)BNB * 192 * 4;
    int* row_off = (int*)w;         w += (size_t)(NN + 4) * 4;
    int* cnt = (int*)w;             w += (size_t)NN * 4;
    int* spart = (int*)w;           w += 256 * 4;
    int* col_src = (int*)w;         w += (size_t)EE * 4;

    float* slot[2] = {accumBase, accumBase + ACST};
    unsigned* amax[2] = {(unsigned*)(accumBase + 192), (unsigned*)(accumBase + ACST + 192)};

    // ---- CSR build ----
    hipMemsetAsync(cnt, 0, (size_t)NN * 4, stream);
    count_deg_kernel<<<(EE + 255) / 256, 256, 0, stream>>>(dstE, cnt, accumBase);
    scan_part_kernel<<<NPART, 256, 0, stream>>>(cnt, spart);
    scan_final_kernel<<<NPART, 256, 0, stream>>>(cnt, spart, row_off);
    scatter_kernel<<<(EE + 255) / 256, 256, 0, stream>>>(srcE, dstE, row_off, cnt, col_src);

    for (int l = 0; l < 3; l++) {
        int sl = l & 1, so = (l + 1) & 1;
        if (l == 0)
            gemm_kernel<128, false><<<(NN + 63) / 64, 256, 0, stream>>>(
                x, Wl[0], asl[0], adl[0], nullptr, nullptr, nullptr,
                bufA, alpha_s, alpha_d, amax[0]);
        else
            gemm_kernel<96, true><<<(NN + 63) / 64, 256, 0, stream>>>(
                bufB, Wl[l], asl[l], adl[l], slot[so], gl[l - 1], btl[l - 1],
                bufA, alpha_s, alpha_d, amax[sl]);
        agg_kernel<<<(NN + 3) / 4, 256, 0, stream>>>(bufA, alpha_s, alpha_d, amax[sl],
                                                     row_off, col_src, bl[l], bufB);
        bn_stats_kernel<<<BNB, 192, 0, stream>>>(bufB, bnpart);
        bn_reduce_kernel<<<1, 256, 0, stream>>>(bnpart, slot[sl], amax[so]);
    }
    fc_kernel<<<(NN + 31) / 32, 256, 0, stream>>>(bufB, slot[0], gl[2], btl[2], fcW, fcb, out);
}